// Round 3
// baseline (1035.556 us; speedup 1.0000x reference)
//
#include <hip/hip_runtime.h>

#define HID 4096
#define QKVDIM 12288
#define SEQ 2048
#define SCALE 0.0625f

typedef unsigned short u16;
typedef unsigned int u32;
typedef __attribute__((ext_vector_type(8))) short short8;   // 8 x bf16 (4 VGPR)
typedef __attribute__((ext_vector_type(4))) float f32x4;
typedef __attribute__((ext_vector_type(4))) unsigned int u32x4;
typedef __attribute__((ext_vector_type(4))) float float4v;

__device__ __forceinline__ u16 f2bf(float f) {
  union { float f; u32 u; } v; v.f = f;
  return (u16)((v.u + 0x7fffu + ((v.u >> 16) & 1u)) >> 16);  // RNE
}
__device__ __forceinline__ float bf2f(u16 h) {
  union { u32 u; float f; } v; v.u = ((u32)h) << 16;
  return v.f;
}
__device__ __forceinline__ u32 pk2(float a, float b) {
  return (u32)f2bf(a) | ((u32)f2bf(b) << 16);
}

// ---------------------------------------------------------------------------
// GEMM: C[M][N] = A[M][K] * B[N][K]^T   (B row-major [N][K], fp32)
// A fp32 (A_BF16=0) or bf16 (A_BF16=1).
// CMODE: 0 = fp32 C plain;  1 = bf16 C into qkv (q/k tiles only, NMAP=1);
//        2 = bf16 C^T into vT[4096][2048] (v tiles, NMAP=2, swapped-mfma).
// 128x128 tile, BK=64, 256 threads (4 waves, each 64x64 out).
// ---------------------------------------------------------------------------
template <int A_BF16, int CMODE>
__global__ __launch_bounds__(256)
void gemm_bt(const void* __restrict__ Av, const float* __restrict__ B,
             void* __restrict__ Cv, int K, int lda, int ldb, int ldc) {
  __shared__ u16 As[128 * 64];
  __shared__ u16 Bs[128 * 64];
  const int t = threadIdx.x;
  const int w = t >> 6, lane = t & 63, g = lane >> 4, c = lane & 15;
  const int m0 = blockIdx.y * 128;
  int n0, vrow0 = 0;
  if (CMODE == 0) {
    n0 = blockIdx.x * 128;
  } else if (CMODE == 1) {  // q/k tiles: bx in 0..63
    const int mp = blockIdx.x >> 3, r = blockIdx.x & 7;
    n0 = mp * 1536 + r * 128 + (r >= 4 ? 512 : 0);
  } else {                  // v tiles: bx in 0..31
    const int mp = blockIdx.x >> 2, r = blockIdx.x & 3;
    n0 = mp * 1536 + 512 + r * 128;
    vrow0 = mp * 512 + r * 128;
  }
  const int wm = (w >> 1) * 64, wn = (w & 1) * 64;

  f32x4 acc[4][4] = {};

  for (int kt = 0; kt < K; kt += 64) {
    __syncthreads();
#pragma unroll
    for (int i = 0; i < 4; ++i) {
      const int Cn = i * 256 + t;
      const int row = Cn >> 3, seg = Cn & 7;
      u32x4 pk;
      if (A_BF16) {
        pk = *(const u32x4*)((const u16*)Av + (size_t)(m0 + row) * lda + kt + seg * 8);
      } else {
        const float* ap = (const float*)Av + (size_t)(m0 + row) * lda + kt + seg * 8;
        float4v f0 = *(const float4v*)ap;
        float4v f1 = *(const float4v*)(ap + 4);
        pk = (u32x4){pk2(f0.x, f0.y), pk2(f0.z, f0.w), pk2(f1.x, f1.y), pk2(f1.z, f1.w)};
      }
      const int idx = (row * 64 + seg * 8) ^ ((row & 7) << 3);
      *(u32x4*)&As[idx] = pk;
    }
#pragma unroll
    for (int i = 0; i < 4; ++i) {
      const int Cn = i * 256 + t;
      const int row = Cn >> 3, seg = Cn & 7;
      const float* bp = B + (size_t)(n0 + row) * ldb + kt + seg * 8;
      float4v f0 = *(const float4v*)bp;
      float4v f1 = *(const float4v*)(bp + 4);
      u32x4 pk = (u32x4){pk2(f0.x, f0.y), pk2(f0.z, f0.w), pk2(f1.x, f1.y), pk2(f1.z, f1.w)};
      const int idx = (row * 64 + seg * 8) ^ ((row & 7) << 3);
      *(u32x4*)&Bs[idx] = pk;
    }
    __syncthreads();

#pragma unroll
    for (int ks = 0; ks < 2; ++ks) {
      const int kk = ks * 32 + g * 8;
      short8 af[4], bf[4];
#pragma unroll
      for (int mi = 0; mi < 4; ++mi) {
        const int r = wm + mi * 16 + c;
        af[mi] = *(const short8*)&As[(r * 64 + kk) ^ ((r & 7) << 3)];
      }
#pragma unroll
      for (int ni = 0; ni < 4; ++ni) {
        const int r = wn + ni * 16 + c;
        bf[ni] = *(const short8*)&Bs[(r * 64 + kk) ^ ((r & 7) << 3)];
      }
#pragma unroll
      for (int mi = 0; mi < 4; ++mi)
#pragma unroll
        for (int ni = 0; ni < 4; ++ni) {
          if (CMODE == 2)  // swapped operands -> accumulates C^T tile
            acc[mi][ni] = __builtin_amdgcn_mfma_f32_16x16x32_bf16(bf[ni], af[mi], acc[mi][ni], 0, 0, 0);
          else
            acc[mi][ni] = __builtin_amdgcn_mfma_f32_16x16x32_bf16(af[mi], bf[ni], acc[mi][ni], 0, 0, 0);
        }
    }
  }

  // epilogue. C/D layout: col = lane&15, row = (lane>>4)*4 + reg  [m89/m91]
#pragma unroll
  for (int mi = 0; mi < 4; ++mi)
#pragma unroll
    for (int ni = 0; ni < 4; ++ni)
#pragma unroll
      for (int r = 0; r < 4; ++r) {
        if (CMODE == 2) {
          // acc = C^T tile: row' = n-offset (g*4+r), col' = s-offset (c)
          const int vr = vrow0 + wn + ni * 16 + g * 4 + r;  // d-row of vT
          const int sc = m0 + wm + mi * 16 + c;             // sequence pos
          ((u16*)Cv)[(size_t)vr * ldc + sc] = f2bf(acc[mi][ni][r]);
        } else {
          const int row = m0 + wm + mi * 16 + g * 4 + r;
          const int col = n0 + wn + ni * 16 + c;
          if (CMODE == 1)
            ((u16*)Cv)[(size_t)row * ldc + col] = f2bf(acc[mi][ni][r]);
          else
            ((float*)Cv)[(size_t)row * ldc + col] = acc[mi][ni][r];
        }
      }
}

// ---------------------------------------------------------------------------
// RoPE (GPT-J interleaved) in-place on q and k sections of qkv (bf16).
// positions may be int32 or int64; detect: positions[1]==1 (int32) vs
// word[1]==0 (hi half of int64 value 0).
// ---------------------------------------------------------------------------
__global__ __launch_bounds__(256)
void rope_kernel(u16* __restrict__ qkv, const int* __restrict__ pos32) {
  const int idx = blockIdx.x * 256 + threadIdx.x;  // SEQ * 16 heads * 32 pairs
  const int s = idx >> 9;
  const int rem = idx & 511;
  const int h = rem >> 5, i = rem & 31;
  const bool is64 = (pos32[1] == 0);
  const int pv = is64 ? pos32[2 * s] : pos32[s];
  const float pos = (float)pv;
  const float inv_freq = expf(-(float)i * (9.210340371976184f / 32.0f));  // 10000^{-i/32}
  const float f = pos * inv_freq;
  const float cs = cosf(f), sn = sinf(f);
  u16* p = qkv + (size_t)s * QKVDIM + (h >> 1) * 1536 + (h & 1) * 256 + 2 * i;
  {  // q
    float x1 = bf2f(p[0]), x2 = bf2f(p[1]);
    p[0] = f2bf(x1 * cs - x2 * sn);
    p[1] = f2bf(x2 * cs + x1 * sn);
  }
  {  // k (+1024)
    u16* pk_ = p + 1024;
    float x1 = bf2f(pk_[0]), x2 = bf2f(pk_[1]);
    pk_[0] = f2bf(x1 * cs - x2 * sn);
    pk_[1] = f2bf(x2 * cs + x1 * sn);
  }
}

// ---------------------------------------------------------------------------
// Flash attention, causal. Block = (64 q-rows) x (1 head); 4 waves x 16 rows.
// D=256, KV tile = 32. K staged XOR-swizzled [32][256] from qkv.
// V staged from pre-transposed vT[4096][2048]: Vl[256 d][40-stride], so the
// PV B-fragment is a plain contiguous short8 (ds_read_b128). No inline asm.
// ---------------------------------------------------------------------------
__global__ __launch_bounds__(256)
void attn_kernel(const u16* __restrict__ qkv, const u16* __restrict__ vT,
                 u16* __restrict__ attnout) {
  __shared__ u16 Kl[32 * 256];
  __shared__ u16 Vl[256 * 40];    // V^T tile: [d][kv], row stride 40 u16
  __shared__ u16 Pl[4][16 * 40];  // per-wave 16x32 P, rows padded to 40

  const int t = threadIdx.x;
  const int w = t >> 6, lane = t & 63, g = lane >> 4, c = lane & 15;
  const int qt = blockIdx.x, head = blockIdx.y;
  const int qrow = qt * 64 + w * 16;
  const int q_off = (head >> 1) * 1536 + (head & 1) * 256;
  const int k_off = q_off + 1024;
  const u16* vTh = vT + (size_t)(head * 256) * SEQ;  // head's 256 d-rows

  // Q fragments: A-operand row = lane&15, k = (lane>>4)*8 (+32 per chunk)
  short8 qf[8];
  {
    const u16* qb = qkv + (size_t)(qrow + c) * QKVDIM + q_off + g * 8;
#pragma unroll
    for (int cc = 0; cc < 8; ++cc) qf[cc] = *(const short8*)(qb + cc * 32);
  }

  f32x4 o[16] = {};
  float mrow[4], lrow[4];
#pragma unroll
  for (int r = 0; r < 4; ++r) { mrow[r] = -3.0e38f; lrow[r] = 0.0f; }

  const int nt = 2 * qt + 2;

  for (int ti = 0; ti < nt; ++ti) {
    const int kv0 = ti * 32;
    __syncthreads();
    // stage K [32][256], read-swizzle-compensated
#pragma unroll
    for (int i = 0; i < 4; ++i) {
      const int Cn = i * 256 + t;
      const int kv = Cn >> 5;
      const int seg = (Cn & 31) ^ (kv & 7);
      u32x4 d = *(const u32x4*)(qkv + (size_t)(kv0 + kv) * QKVDIM + k_off + seg * 8);
      *(u32x4*)&Kl[Cn * 8] = d;
    }
    // stage V^T rows: task n -> d = n>>2, q8 = (n&3)*8 (8 kv per 16B chunk)
#pragma unroll
    for (int i = 0; i < 4; ++i) {
      const int n = i * 256 + t;
      const int d = n >> 2, q8 = (n & 3) * 8;
      u32x4 v = *(const u32x4*)(vTh + (size_t)d * SEQ + kv0 + q8);
      *(u32x4*)&Vl[d * 40 + q8] = v;
    }
    __syncthreads();

    if (kv0 <= qrow + 15) {  // wave-level causal early-out
      // S = Q K^T : two 16x16 output tiles (kv 0..15, 16..31)
      f32x4 s0 = {}, s1 = {};
#pragma unroll
      for (int cc = 0; cc < 8; ++cc) {
        const int d = cc * 32 + g * 8;
        {
          const int kv = c;
          short8 kf = *(const short8*)&Kl[(kv * 256 + d) ^ ((kv & 7) << 3)];
          s0 = __builtin_amdgcn_mfma_f32_16x16x32_bf16(qf[cc], kf, s0, 0, 0, 0);
        }
        {
          const int kv = 16 + c;
          short8 kf = *(const short8*)&Kl[(kv * 256 + d) ^ ((kv & 7) << 3)];
          s1 = __builtin_amdgcn_mfma_f32_16x16x32_bf16(qf[cc], kf, s1, 0, 0, 0);
        }
      }

      // online softmax (rows = g*4+r, kv spread over the 16 lanes of the group)
      const bool domask = (kv0 + 31 > qrow);
      float sv0[4], sv1[4];
#pragma unroll
      for (int r = 0; r < 4; ++r) {
        sv0[r] = s0[r] * SCALE;
        sv1[r] = s1[r] * SCALE;
        if (domask) {
          const int qg = qrow + g * 4 + r;
          if (kv0 + c > qg) sv0[r] = -3.0e38f;
          if (kv0 + 16 + c > qg) sv1[r] = -3.0e38f;
        }
      }
      float corr[4];
#pragma unroll
      for (int r = 0; r < 4; ++r) {
        float tm = fmaxf(sv0[r], sv1[r]);
#pragma unroll
        for (int off = 1; off < 16; off <<= 1) tm = fmaxf(tm, __shfl_xor(tm, off));
        const float mnew = fmaxf(mrow[r], tm);
        corr[r] = __expf(mrow[r] - mnew);
        mrow[r] = mnew;
        const float p0 = __expf(sv0[r] - mnew);
        const float p1 = __expf(sv1[r] - mnew);
        Pl[w][(g * 4 + r) * 40 + c] = f2bf(p0);
        Pl[w][(g * 4 + r) * 40 + 16 + c] = f2bf(p1);
        float rs = p0 + p1;
#pragma unroll
        for (int off = 1; off < 16; off <<= 1) rs += __shfl_xor(rs, off);
        lrow[r] = lrow[r] * corr[r] + rs;
      }
#pragma unroll
      for (int dt = 0; dt < 16; ++dt)
#pragma unroll
        for (int r = 0; r < 4; ++r) o[dt][r] *= corr[r];

      // PV: A = P[q=c][kv=g*8+j], B = V^T[d=dt*16+c][kv=g*8+j]
      const short8 pa = *(const short8*)&Pl[w][c * 40 + g * 8];
#pragma unroll
      for (int dt = 0; dt < 16; ++dt) {
        const short8 bv = *(const short8*)&Vl[(dt * 16 + c) * 40 + g * 8];
        o[dt] = __builtin_amdgcn_mfma_f32_16x16x32_bf16(pa, bv, o[dt], 0, 0, 0);
      }
    }
  }

  // epilogue: normalize and write attn[s][head*256 + d] (bf16)
  float inv[4];
#pragma unroll
  for (int r = 0; r < 4; ++r) inv[r] = 1.0f / lrow[r];
#pragma unroll
  for (int dt = 0; dt < 16; ++dt)
#pragma unroll
    for (int r = 0; r < 4; ++r) {
      const int row = qrow + g * 4 + r;
      attnout[(size_t)row * HID + head * 256 + dt * 16 + c] = f2bf(o[dt][r] * inv[r]);
    }
}

// ---------------------------------------------------------------------------
extern "C" void kernel_launch(void* const* d_in, const int* in_sizes, int n_in,
                              void* d_out, int out_size, void* d_ws, size_t ws_size,
                              hipStream_t stream) {
  const float* hidden = (const float*)d_in[0];      // [2048][4096] fp32
  const int* positions = (const int*)d_in[1];       // [2048] int32 or int64
  const float* w_qkv = (const float*)d_in[2];       // [12288][4096] fp32
  const float* w_out = (const float*)d_in[3];       // [4096][4096] fp32
  float* out = (float*)d_out;                       // [2048][4096] fp32

  u16* qkv = (u16*)d_ws;                            // [2048][12288] bf16 (48 MiB)
  u16* attn = qkv + (size_t)SEQ * QKVDIM;           // [2048][4096] bf16 (16 MiB)
  u16* vT = attn + (size_t)SEQ * HID;               // [4096][2048] bf16 (16 MiB)

  // 1a) q/k tiles of QKV = hidden * w_qkv^T -> qkv (bf16)
  gemm_bt<0, 1><<<dim3(64, SEQ / 128), 256, 0, stream>>>(
      hidden, w_qkv, qkv, HID, HID, HID, QKVDIM);
  // 1b) v tiles, swapped-mfma -> vT[4096][2048] (bf16, transposed)
  gemm_bt<0, 2><<<dim3(32, SEQ / 128), 256, 0, stream>>>(
      hidden, w_qkv, vT, HID, HID, HID, SEQ);
  // 2) RoPE on q,k (in place)
  rope_kernel<<<(SEQ * 512) / 256, 256, 0, stream>>>(qkv, positions);
  // 3) causal flash attention -> attn (bf16)
  attn_kernel<<<dim3(SEQ / 64, 16), 256, 0, stream>>>(qkv, vT, attn);
  // 4) out = attn * w_out^T (fp32)
  gemm_bt<1, 0><<<dim3(HID / 128, SEQ / 128), 256, 0, stream>>>(
      attn, w_out, out, HID, HID, HID, HID);
}

// Round 4
// 768.481 us; speedup vs baseline: 1.3475x; 1.3475x over previous
//
#include <hip/hip_runtime.h>

#define HID 4096
#define QKVDIM 12288
#define SEQ 2048
#define SCALE 0.0625f

typedef unsigned short u16;
typedef unsigned int u32;
typedef __attribute__((ext_vector_type(8))) short short8;   // 8 x bf16 (4 VGPR)
typedef __attribute__((ext_vector_type(4))) float f32x4;
typedef __attribute__((ext_vector_type(4))) unsigned int u32x4;
typedef __attribute__((ext_vector_type(4))) float float4v;

__device__ __forceinline__ u16 f2bf(float f) {
  union { float f; u32 u; } v; v.f = f;
  return (u16)((v.u + 0x7fffu + ((v.u >> 16) & 1u)) >> 16);  // RNE
}
__device__ __forceinline__ float bf2f(u16 h) {
  union { u32 u; float f; } v; v.u = ((u32)h) << 16;
  return v.f;
}
__device__ __forceinline__ u32 pk2(float a, float b) {
  return (u32)f2bf(a) | ((u32)f2bf(b) << 16);
}

// ---------------------------------------------------------------------------
// fp32 -> bf16 bulk convert (8 elems/thread, grid-stride)
// ---------------------------------------------------------------------------
__global__ __launch_bounds__(256)
void conv_kernel(const float* __restrict__ in, u16* __restrict__ out, int n8) {
  for (int i = blockIdx.x * 256 + threadIdx.x; i < n8; i += gridDim.x * 256) {
    const float* p = in + (size_t)i * 8;
    float4v f0 = *(const float4v*)p;
    float4v f1 = *(const float4v*)(p + 4);
    u32x4 pk = (u32x4){pk2(f0.x, f0.y), pk2(f0.z, f0.w), pk2(f1.x, f1.y), pk2(f1.z, f1.w)};
    *(u32x4*)(out + (size_t)i * 8) = pk;
  }
}

// ---------------------------------------------------------------------------
// FAST GEMM (m97 structure): C[M][N] = A[M][K] * B[N][K]^T, A,B bf16.
// global_load_lds width=16 staging, linear LDS, 128x128 tile, BK=64, 4 waves.
// CMODE: 0 = fp32 C;  1 = bf16 C into qkv q/k tiles;  2 = bf16 C^T into vT.
// ---------------------------------------------------------------------------
template <int CMODE>
__global__ __launch_bounds__(256)
void gemm_fast(const u16* __restrict__ A, const u16* __restrict__ B,
               void* __restrict__ Cv, int K, int lda, int ldb, int ldc) {
  __shared__ __align__(16) u16 As[128 * 64];
  __shared__ __align__(16) u16 Bs[128 * 64];
  const int t = threadIdx.x;
  const int w = t >> 6, lane = t & 63, g = lane >> 4, c = lane & 15;
  const int m0 = blockIdx.y * 128;
  int n0, vrow0 = 0;
  if (CMODE == 0) {
    n0 = blockIdx.x * 128;
  } else if (CMODE == 1) {  // q/k tiles: bx in 0..63
    const int mp = blockIdx.x >> 3, r = blockIdx.x & 7;
    n0 = mp * 1536 + r * 128 + (r >= 4 ? 512 : 0);
  } else {                  // v tiles: bx in 0..31
    const int mp = blockIdx.x >> 2, r = blockIdx.x & 3;
    n0 = mp * 1536 + 512 + r * 128;
    vrow0 = mp * 512 + r * 128;
  }
  const int wm = (w >> 1) * 64, wn = (w & 1) * 64;

  // staging: wave w covers rows [w*32, w*32+32); lane -> (row=lane>>3, col=(lane&7)*8)
  const u16* Ab = A + (size_t)(m0 + w * 32 + (lane >> 3)) * lda + (lane & 7) * 8;
  const u16* Bb = B + (size_t)(n0 + w * 32 + (lane >> 3)) * ldb + (lane & 7) * 8;
  u16* AsW = &As[w * 32 * 64];  // wave-uniform LDS base
  u16* BsW = &Bs[w * 32 * 64];

  f32x4 acc[4][4] = {};

  for (int kt = 0; kt < K; kt += 64) {
    __syncthreads();  // previous compute done before overwrite
#pragma unroll
    for (int i = 0; i < 4; ++i)
      __builtin_amdgcn_global_load_lds(
          (const __attribute__((address_space(1))) u32*)(Ab + kt + i * 8 * lda),
          (__attribute__((address_space(3))) u32*)(AsW + i * 8 * 64), 16, 0, 0);
#pragma unroll
    for (int i = 0; i < 4; ++i)
      __builtin_amdgcn_global_load_lds(
          (const __attribute__((address_space(1))) u32*)(Bb + kt + i * 8 * ldb),
          (__attribute__((address_space(3))) u32*)(BsW + i * 8 * 64), 16, 0, 0);
    __syncthreads();  // compiler drains vmcnt(0) before this barrier

#pragma unroll
    for (int ks = 0; ks < 2; ++ks) {
      const int kk = ks * 32 + g * 8;
      short8 af[4], bf[4];
#pragma unroll
      for (int mi = 0; mi < 4; ++mi)
        af[mi] = *(const short8*)&As[(wm + mi * 16 + c) * 64 + kk];
#pragma unroll
      for (int ni = 0; ni < 4; ++ni)
        bf[ni] = *(const short8*)&Bs[(wn + ni * 16 + c) * 64 + kk];
#pragma unroll
      for (int mi = 0; mi < 4; ++mi)
#pragma unroll
        for (int ni = 0; ni < 4; ++ni)
          acc[mi][ni] = (CMODE == 2)
              ? __builtin_amdgcn_mfma_f32_16x16x32_bf16(bf[ni], af[mi], acc[mi][ni], 0, 0, 0)
              : __builtin_amdgcn_mfma_f32_16x16x32_bf16(af[mi], bf[ni], acc[mi][ni], 0, 0, 0);
    }
  }

  // epilogue. C/D layout: col = lane&15, row = (lane>>4)*4 + reg  [m89/m91]
#pragma unroll
  for (int mi = 0; mi < 4; ++mi)
#pragma unroll
    for (int ni = 0; ni < 4; ++ni)
#pragma unroll
      for (int r = 0; r < 4; ++r) {
        if (CMODE == 2) {
          const int vr = vrow0 + wn + ni * 16 + g * 4 + r;  // d-row of vT
          const int sc = m0 + wm + mi * 16 + c;             // sequence pos
          ((u16*)Cv)[(size_t)vr * ldc + sc] = f2bf(acc[mi][ni][r]);
        } else {
          const int row = m0 + wm + mi * 16 + g * 4 + r;
          const int col = n0 + wn + ni * 16 + c;
          if (CMODE == 1)
            ((u16*)Cv)[(size_t)row * ldc + col] = f2bf(acc[mi][ni][r]);
          else
            ((float*)Cv)[(size_t)row * ldc + col] = acc[mi][ni][r];
        }
      }
}

// ---------------------------------------------------------------------------
// FALLBACK GEMM (round-3): fp32 B, reg-staged conversion. Used only if ws is
// too small for the bf16 weight copies.
// ---------------------------------------------------------------------------
template <int A_BF16, int CMODE>
__global__ __launch_bounds__(256)
void gemm_bt(const void* __restrict__ Av, const float* __restrict__ B,
             void* __restrict__ Cv, int K, int lda, int ldb, int ldc) {
  __shared__ u16 As[128 * 64];
  __shared__ u16 Bs[128 * 64];
  const int t = threadIdx.x;
  const int w = t >> 6, lane = t & 63, g = lane >> 4, c = lane & 15;
  const int m0 = blockIdx.y * 128;
  int n0, vrow0 = 0;
  if (CMODE == 0) {
    n0 = blockIdx.x * 128;
  } else if (CMODE == 1) {
    const int mp = blockIdx.x >> 3, r = blockIdx.x & 7;
    n0 = mp * 1536 + r * 128 + (r >= 4 ? 512 : 0);
  } else {
    const int mp = blockIdx.x >> 2, r = blockIdx.x & 3;
    n0 = mp * 1536 + 512 + r * 128;
    vrow0 = mp * 512 + r * 128;
  }
  const int wm = (w >> 1) * 64, wn = (w & 1) * 64;

  f32x4 acc[4][4] = {};

  for (int kt = 0; kt < K; kt += 64) {
    __syncthreads();
#pragma unroll
    for (int i = 0; i < 4; ++i) {
      const int Cn = i * 256 + t;
      const int row = Cn >> 3, seg = Cn & 7;
      u32x4 pk;
      if (A_BF16) {
        pk = *(const u32x4*)((const u16*)Av + (size_t)(m0 + row) * lda + kt + seg * 8);
      } else {
        const float* ap = (const float*)Av + (size_t)(m0 + row) * lda + kt + seg * 8;
        float4v f0 = *(const float4v*)ap;
        float4v f1 = *(const float4v*)(ap + 4);
        pk = (u32x4){pk2(f0.x, f0.y), pk2(f0.z, f0.w), pk2(f1.x, f1.y), pk2(f1.z, f1.w)};
      }
      const int idx = (row * 64 + seg * 8) ^ ((row & 7) << 3);
      *(u32x4*)&As[idx] = pk;
    }
#pragma unroll
    for (int i = 0; i < 4; ++i) {
      const int Cn = i * 256 + t;
      const int row = Cn >> 3, seg = Cn & 7;
      const float* bp = B + (size_t)(n0 + row) * ldb + kt + seg * 8;
      float4v f0 = *(const float4v*)bp;
      float4v f1 = *(const float4v*)(bp + 4);
      u32x4 pk = (u32x4){pk2(f0.x, f0.y), pk2(f0.z, f0.w), pk2(f1.x, f1.y), pk2(f1.z, f1.w)};
      const int idx = (row * 64 + seg * 8) ^ ((row & 7) << 3);
      *(u32x4*)&Bs[idx] = pk;
    }
    __syncthreads();

#pragma unroll
    for (int ks = 0; ks < 2; ++ks) {
      const int kk = ks * 32 + g * 8;
      short8 af[4], bf[4];
#pragma unroll
      for (int mi = 0; mi < 4; ++mi) {
        const int r = wm + mi * 16 + c;
        af[mi] = *(const short8*)&As[(r * 64 + kk) ^ ((r & 7) << 3)];
      }
#pragma unroll
      for (int ni = 0; ni < 4; ++ni) {
        const int r = wn + ni * 16 + c;
        bf[ni] = *(const short8*)&Bs[(r * 64 + kk) ^ ((r & 7) << 3)];
      }
#pragma unroll
      for (int mi = 0; mi < 4; ++mi)
#pragma unroll
        for (int ni = 0; ni < 4; ++ni) {
          if (CMODE == 2)
            acc[mi][ni] = __builtin_amdgcn_mfma_f32_16x16x32_bf16(bf[ni], af[mi], acc[mi][ni], 0, 0, 0);
          else
            acc[mi][ni] = __builtin_amdgcn_mfma_f32_16x16x32_bf16(af[mi], bf[ni], acc[mi][ni], 0, 0, 0);
        }
    }
  }

#pragma unroll
  for (int mi = 0; mi < 4; ++mi)
#pragma unroll
    for (int ni = 0; ni < 4; ++ni)
#pragma unroll
      for (int r = 0; r < 4; ++r) {
        if (CMODE == 2) {
          const int vr = vrow0 + wn + ni * 16 + g * 4 + r;
          const int sc = m0 + wm + mi * 16 + c;
          ((u16*)Cv)[(size_t)vr * ldc + sc] = f2bf(acc[mi][ni][r]);
        } else {
          const int row = m0 + wm + mi * 16 + g * 4 + r;
          const int col = n0 + wn + ni * 16 + c;
          if (CMODE == 1)
            ((u16*)Cv)[(size_t)row * ldc + col] = f2bf(acc[mi][ni][r]);
          else
            ((float*)Cv)[(size_t)row * ldc + col] = acc[mi][ni][r];
        }
      }
}

// ---------------------------------------------------------------------------
// RoPE (GPT-J interleaved) in-place on q and k sections of qkv (bf16).
// positions may be int32 or int64 (jax x64): positions[1]==1 -> int32.
// ---------------------------------------------------------------------------
__global__ __launch_bounds__(256)
void rope_kernel(u16* __restrict__ qkv, const int* __restrict__ pos32) {
  const int idx = blockIdx.x * 256 + threadIdx.x;  // SEQ * 16 heads * 32 pairs
  const int s = idx >> 9;
  const int rem = idx & 511;
  const int h = rem >> 5, i = rem & 31;
  const bool is64 = (pos32[1] == 0);
  const int pv = is64 ? pos32[2 * s] : pos32[s];
  const float pos = (float)pv;
  const float inv_freq = expf(-(float)i * (9.210340371976184f / 32.0f));  // 10000^{-i/32}
  const float f = pos * inv_freq;
  const float cs = cosf(f), sn = sinf(f);
  u16* p = qkv + (size_t)s * QKVDIM + (h >> 1) * 1536 + (h & 1) * 256 + 2 * i;
  {  // q
    float x1 = bf2f(p[0]), x2 = bf2f(p[1]);
    p[0] = f2bf(x1 * cs - x2 * sn);
    p[1] = f2bf(x2 * cs + x1 * sn);
  }
  {  // k (+1024)
    u16* pk_ = p + 1024;
    float x1 = bf2f(pk_[0]), x2 = bf2f(pk_[1]);
    pk_[0] = f2bf(x1 * cs - x2 * sn);
    pk_[1] = f2bf(x2 * cs + x1 * sn);
  }
}

// ---------------------------------------------------------------------------
// Flash attention, causal. Block = (64 q-rows) x (1 head); 4 waves x 16 rows.
// D=256, KV tile = 32. K staged XOR-swizzled [32][256] from qkv.
// V staged from pre-transposed vT[4096][2048]: Vl[256 d][40-stride].
// ---------------------------------------------------------------------------
__global__ __launch_bounds__(256)
void attn_kernel(const u16* __restrict__ qkv, const u16* __restrict__ vT,
                 u16* __restrict__ attnout) {
  __shared__ u16 Kl[32 * 256];
  __shared__ u16 Vl[256 * 40];
  __shared__ u16 Pl[4][16 * 40];

  const int t = threadIdx.x;
  const int w = t >> 6, lane = t & 63, g = lane >> 4, c = lane & 15;
  const int qt = blockIdx.x, head = blockIdx.y;
  const int qrow = qt * 64 + w * 16;
  const int q_off = (head >> 1) * 1536 + (head & 1) * 256;
  const int k_off = q_off + 1024;
  const u16* vTh = vT + (size_t)(head * 256) * SEQ;

  short8 qf[8];
  {
    const u16* qb = qkv + (size_t)(qrow + c) * QKVDIM + q_off + g * 8;
#pragma unroll
    for (int cc = 0; cc < 8; ++cc) qf[cc] = *(const short8*)(qb + cc * 32);
  }

  f32x4 o[16] = {};
  float mrow[4], lrow[4];
#pragma unroll
  for (int r = 0; r < 4; ++r) { mrow[r] = -3.0e38f; lrow[r] = 0.0f; }

  const int nt = 2 * qt + 2;

  for (int ti = 0; ti < nt; ++ti) {
    const int kv0 = ti * 32;
    __syncthreads();
#pragma unroll
    for (int i = 0; i < 4; ++i) {
      const int Cn = i * 256 + t;
      const int kv = Cn >> 5;
      const int seg = (Cn & 31) ^ (kv & 7);
      u32x4 d = *(const u32x4*)(qkv + (size_t)(kv0 + kv) * QKVDIM + k_off + seg * 8);
      *(u32x4*)&Kl[Cn * 8] = d;
    }
#pragma unroll
    for (int i = 0; i < 4; ++i) {
      const int n = i * 256 + t;
      const int d = n >> 2, q8 = (n & 3) * 8;
      u32x4 v = *(const u32x4*)(vTh + (size_t)d * SEQ + kv0 + q8);
      *(u32x4*)&Vl[d * 40 + q8] = v;
    }
    __syncthreads();

    if (kv0 <= qrow + 15) {
      f32x4 s0 = {}, s1 = {};
#pragma unroll
      for (int cc = 0; cc < 8; ++cc) {
        const int d = cc * 32 + g * 8;
        {
          const int kv = c;
          short8 kf = *(const short8*)&Kl[(kv * 256 + d) ^ ((kv & 7) << 3)];
          s0 = __builtin_amdgcn_mfma_f32_16x16x32_bf16(qf[cc], kf, s0, 0, 0, 0);
        }
        {
          const int kv = 16 + c;
          short8 kf = *(const short8*)&Kl[(kv * 256 + d) ^ ((kv & 7) << 3)];
          s1 = __builtin_amdgcn_mfma_f32_16x16x32_bf16(qf[cc], kf, s1, 0, 0, 0);
        }
      }

      const bool domask = (kv0 + 31 > qrow);
      float sv0[4], sv1[4];
#pragma unroll
      for (int r = 0; r < 4; ++r) {
        sv0[r] = s0[r] * SCALE;
        sv1[r] = s1[r] * SCALE;
        if (domask) {
          const int qg = qrow + g * 4 + r;
          if (kv0 + c > qg) sv0[r] = -3.0e38f;
          if (kv0 + 16 + c > qg) sv1[r] = -3.0e38f;
        }
      }
      float corr[4];
#pragma unroll
      for (int r = 0; r < 4; ++r) {
        float tm = fmaxf(sv0[r], sv1[r]);
#pragma unroll
        for (int off = 1; off < 16; off <<= 1) tm = fmaxf(tm, __shfl_xor(tm, off));
        const float mnew = fmaxf(mrow[r], tm);
        corr[r] = __expf(mrow[r] - mnew);
        mrow[r] = mnew;
        const float p0 = __expf(sv0[r] - mnew);
        const float p1 = __expf(sv1[r] - mnew);
        Pl[w][(g * 4 + r) * 40 + c] = f2bf(p0);
        Pl[w][(g * 4 + r) * 40 + 16 + c] = f2bf(p1);
        float rs = p0 + p1;
#pragma unroll
        for (int off = 1; off < 16; off <<= 1) rs += __shfl_xor(rs, off);
        lrow[r] = lrow[r] * corr[r] + rs;
      }
#pragma unroll
      for (int dt = 0; dt < 16; ++dt)
#pragma unroll
        for (int r = 0; r < 4; ++r) o[dt][r] *= corr[r];

      const short8 pa = *(const short8*)&Pl[w][c * 40 + g * 8];
#pragma unroll
      for (int dt = 0; dt < 16; ++dt) {
        const short8 bv = *(const short8*)&Vl[(dt * 16 + c) * 40 + g * 8];
        o[dt] = __builtin_amdgcn_mfma_f32_16x16x32_bf16(pa, bv, o[dt], 0, 0, 0);
      }
    }
  }

  float inv[4];
#pragma unroll
  for (int r = 0; r < 4; ++r) inv[r] = 1.0f / lrow[r];
#pragma unroll
  for (int dt = 0; dt < 16; ++dt)
#pragma unroll
    for (int r = 0; r < 4; ++r) {
      const int row = qrow + g * 4 + r;
      attnout[(size_t)row * HID + head * 256 + dt * 16 + c] = f2bf(o[dt][r] * inv[r]);
    }
}

// ---------------------------------------------------------------------------
extern "C" void kernel_launch(void* const* d_in, const int* in_sizes, int n_in,
                              void* d_out, int out_size, void* d_ws, size_t ws_size,
                              hipStream_t stream) {
  const float* hidden = (const float*)d_in[0];      // [2048][4096] fp32
  const int* positions = (const int*)d_in[1];       // [2048] int32 or int64
  const float* w_qkv = (const float*)d_in[2];       // [12288][4096] fp32
  const float* w_out = (const float*)d_in[3];       // [4096][4096] fp32
  float* out = (float*)d_out;                       // [2048][4096] fp32

  u16* qkv = (u16*)d_ws;                            // 48 MiB
  u16* attn = qkv + (size_t)SEQ * QKVDIM;           // 16 MiB
  u16* vT = attn + (size_t)SEQ * HID;               // 16 MiB
  u16* hid_bf = vT + (size_t)HID * SEQ;             // 16 MiB
  u16* wqkv_bf = hid_bf + (size_t)SEQ * HID;        // 96 MiB
  u16* wout_bf = wqkv_bf + (size_t)QKVDIM * HID;    // 32 MiB

  const size_t need = ((size_t)SEQ * QKVDIM + (size_t)SEQ * HID * 2 +
                       (size_t)HID * SEQ + (size_t)QKVDIM * HID +
                       (size_t)HID * HID) * 2;      // 224 MiB

  if (ws_size >= need) {
    // 0) bulk fp32->bf16 weight/activation conversion
    conv_kernel<<<2048, 256, 0, stream>>>(hidden, hid_bf, SEQ * HID / 8);
    conv_kernel<<<2048, 256, 0, stream>>>(w_qkv, wqkv_bf, QKVDIM * HID / 8);
    conv_kernel<<<2048, 256, 0, stream>>>(w_out, wout_bf, HID * HID / 8);
    // 1a) q/k tiles of QKV -> qkv (bf16)
    gemm_fast<1><<<dim3(64, SEQ / 128), 256, 0, stream>>>(
        hid_bf, wqkv_bf, qkv, HID, HID, HID, QKVDIM);
    // 1b) v tiles, swapped-mfma -> vT (bf16, transposed)
    gemm_fast<2><<<dim3(32, SEQ / 128), 256, 0, stream>>>(
        hid_bf, wqkv_bf, vT, HID, HID, HID, SEQ);
    rope_kernel<<<(SEQ * 512) / 256, 256, 0, stream>>>(qkv, positions);
    attn_kernel<<<dim3(SEQ / 64, 16), 256, 0, stream>>>(qkv, vT, attn);
    // 4) out = attn * w_out^T (fp32)
    gemm_fast<0><<<dim3(HID / 128, SEQ / 128), 256, 0, stream>>>(
        attn, wout_bf, out, HID, HID, HID, HID);
  } else {
    gemm_bt<0, 1><<<dim3(64, SEQ / 128), 256, 0, stream>>>(
        hidden, w_qkv, qkv, HID, HID, HID, QKVDIM);
    gemm_bt<0, 2><<<dim3(32, SEQ / 128), 256, 0, stream>>>(
        hidden, w_qkv, vT, HID, HID, HID, SEQ);
    rope_kernel<<<(SEQ * 512) / 256, 256, 0, stream>>>(qkv, positions);
    attn_kernel<<<dim3(SEQ / 64, 16), 256, 0, stream>>>(qkv, vT, attn);
    gemm_bt<1, 0><<<dim3(HID / 128, SEQ / 128), 256, 0, stream>>>(
        attn, w_out, out, HID, HID, HID, HID);
  }
}

// Round 5
// 667.073 us; speedup vs baseline: 1.5524x; 1.1520x over previous
//
#include <hip/hip_runtime.h>

#define HID 4096
#define QKVDIM 12288
#define SEQ 2048
#define SCALE 0.0625f

typedef unsigned short u16;
typedef unsigned int u32;
typedef __attribute__((ext_vector_type(8))) short short8;   // 8 x bf16 (4 VGPR)
typedef __attribute__((ext_vector_type(4))) float f32x4;
typedef __attribute__((ext_vector_type(4))) unsigned int u32x4;
typedef __attribute__((ext_vector_type(4))) float float4v;

__device__ __forceinline__ u16 f2bf(float f) {
  union { float f; u32 u; } v; v.f = f;
  return (u16)((v.u + 0x7fffu + ((v.u >> 16) & 1u)) >> 16);  // RNE
}
__device__ __forceinline__ float bf2f(u16 h) {
  union { u32 u; float f; } v; v.u = ((u32)h) << 16;
  return v.f;
}
__device__ __forceinline__ u32 pk2(float a, float b) {
  return (u32)f2bf(a) | ((u32)f2bf(b) << 16);
}

// ---------------------------------------------------------------------------
// fp32 -> bf16 bulk convert (8 elems/thread, grid-stride)
// ---------------------------------------------------------------------------
__global__ __launch_bounds__(256)
void conv_kernel(const float* __restrict__ in, u16* __restrict__ out, int n8) {
  for (int i = blockIdx.x * 256 + threadIdx.x; i < n8; i += gridDim.x * 256) {
    const float* p = in + (size_t)i * 8;
    float4v f0 = *(const float4v*)p;
    float4v f1 = *(const float4v*)(p + 4);
    u32x4 pk = (u32x4){pk2(f0.x, f0.y), pk2(f0.z, f0.w), pk2(f1.x, f1.y), pk2(f1.z, f1.w)};
    *(u32x4*)(out + (size_t)i * 8) = pk;
  }
}

// ---------------------------------------------------------------------------
// FAST GEMM (m97 structure): C[M][N] = A[M][K] * B[N][K]^T, A,B bf16.
// global_load_lds width=16 staging, linear LDS, 128x128 tile, BK=64, 4 waves.
// CMODE: 0 = fp32 C;  1 = bf16 C into qkv q/k tiles;  2 = bf16 C^T into vT.
// ---------------------------------------------------------------------------
template <int CMODE>
__global__ __launch_bounds__(256)
void gemm_fast(const u16* __restrict__ A, const u16* __restrict__ B,
               void* __restrict__ Cv, int K, int lda, int ldb, int ldc) {
  __shared__ __align__(16) u16 As[128 * 64];
  __shared__ __align__(16) u16 Bs[128 * 64];
  const int t = threadIdx.x;
  const int w = t >> 6, lane = t & 63, g = lane >> 4, c = lane & 15;
  const int m0 = blockIdx.y * 128;
  int n0, vrow0 = 0;
  if (CMODE == 0) {
    n0 = blockIdx.x * 128;
  } else if (CMODE == 1) {  // q/k tiles: bx in 0..63
    const int mp = blockIdx.x >> 3, r = blockIdx.x & 7;
    n0 = mp * 1536 + r * 128 + (r >= 4 ? 512 : 0);
  } else {                  // v tiles: bx in 0..31
    const int mp = blockIdx.x >> 2, r = blockIdx.x & 3;
    n0 = mp * 1536 + 512 + r * 128;
    vrow0 = mp * 512 + r * 128;
  }
  const int wm = (w >> 1) * 64, wn = (w & 1) * 64;

  const u16* Ab = A + (size_t)(m0 + w * 32 + (lane >> 3)) * lda + (lane & 7) * 8;
  const u16* Bb = B + (size_t)(n0 + w * 32 + (lane >> 3)) * ldb + (lane & 7) * 8;
  u16* AsW = &As[w * 32 * 64];  // wave-uniform LDS base
  u16* BsW = &Bs[w * 32 * 64];

  f32x4 acc[4][4] = {};

  for (int kt = 0; kt < K; kt += 64) {
    __syncthreads();
#pragma unroll
    for (int i = 0; i < 4; ++i)
      __builtin_amdgcn_global_load_lds(
          (const __attribute__((address_space(1))) u32*)(Ab + kt + i * 8 * lda),
          (__attribute__((address_space(3))) u32*)(AsW + i * 8 * 64), 16, 0, 0);
#pragma unroll
    for (int i = 0; i < 4; ++i)
      __builtin_amdgcn_global_load_lds(
          (const __attribute__((address_space(1))) u32*)(Bb + kt + i * 8 * ldb),
          (__attribute__((address_space(3))) u32*)(BsW + i * 8 * 64), 16, 0, 0);
    __syncthreads();

#pragma unroll
    for (int ks = 0; ks < 2; ++ks) {
      const int kk = ks * 32 + g * 8;
      short8 af[4], bf[4];
#pragma unroll
      for (int mi = 0; mi < 4; ++mi)
        af[mi] = *(const short8*)&As[(wm + mi * 16 + c) * 64 + kk];
#pragma unroll
      for (int ni = 0; ni < 4; ++ni)
        bf[ni] = *(const short8*)&Bs[(wn + ni * 16 + c) * 64 + kk];
#pragma unroll
      for (int mi = 0; mi < 4; ++mi)
#pragma unroll
        for (int ni = 0; ni < 4; ++ni)
          acc[mi][ni] = (CMODE == 2)
              ? __builtin_amdgcn_mfma_f32_16x16x32_bf16(bf[ni], af[mi], acc[mi][ni], 0, 0, 0)
              : __builtin_amdgcn_mfma_f32_16x16x32_bf16(af[mi], bf[ni], acc[mi][ni], 0, 0, 0);
    }
  }

#pragma unroll
  for (int mi = 0; mi < 4; ++mi)
#pragma unroll
    for (int ni = 0; ni < 4; ++ni)
#pragma unroll
      for (int r = 0; r < 4; ++r) {
        if (CMODE == 2) {
          const int vr = vrow0 + wn + ni * 16 + g * 4 + r;
          const int sc = m0 + wm + mi * 16 + c;
          ((u16*)Cv)[(size_t)vr * ldc + sc] = f2bf(acc[mi][ni][r]);
        } else {
          const int row = m0 + wm + mi * 16 + g * 4 + r;
          const int col = n0 + wn + ni * 16 + c;
          if (CMODE == 1)
            ((u16*)Cv)[(size_t)row * ldc + col] = f2bf(acc[mi][ni][r]);
          else
            ((float*)Cv)[(size_t)row * ldc + col] = acc[mi][ni][r];
        }
      }
}

// ---------------------------------------------------------------------------
// FALLBACK GEMM: fp32 B, reg-staged conversion (used only if ws too small).
// ---------------------------------------------------------------------------
template <int A_BF16, int CMODE>
__global__ __launch_bounds__(256)
void gemm_bt(const void* __restrict__ Av, const float* __restrict__ B,
             void* __restrict__ Cv, int K, int lda, int ldb, int ldc) {
  __shared__ u16 As[128 * 64];
  __shared__ u16 Bs[128 * 64];
  const int t = threadIdx.x;
  const int w = t >> 6, lane = t & 63, g = lane >> 4, c = lane & 15;
  const int m0 = blockIdx.y * 128;
  int n0, vrow0 = 0;
  if (CMODE == 0) {
    n0 = blockIdx.x * 128;
  } else if (CMODE == 1) {
    const int mp = blockIdx.x >> 3, r = blockIdx.x & 7;
    n0 = mp * 1536 + r * 128 + (r >= 4 ? 512 : 0);
  } else {
    const int mp = blockIdx.x >> 2, r = blockIdx.x & 3;
    n0 = mp * 1536 + 512 + r * 128;
    vrow0 = mp * 512 + r * 128;
  }
  const int wm = (w >> 1) * 64, wn = (w & 1) * 64;

  f32x4 acc[4][4] = {};

  for (int kt = 0; kt < K; kt += 64) {
    __syncthreads();
#pragma unroll
    for (int i = 0; i < 4; ++i) {
      const int Cn = i * 256 + t;
      const int row = Cn >> 3, seg = Cn & 7;
      u32x4 pk;
      if (A_BF16) {
        pk = *(const u32x4*)((const u16*)Av + (size_t)(m0 + row) * lda + kt + seg * 8);
      } else {
        const float* ap = (const float*)Av + (size_t)(m0 + row) * lda + kt + seg * 8;
        float4v f0 = *(const float4v*)ap;
        float4v f1 = *(const float4v*)(ap + 4);
        pk = (u32x4){pk2(f0.x, f0.y), pk2(f0.z, f0.w), pk2(f1.x, f1.y), pk2(f1.z, f1.w)};
      }
      const int idx = (row * 64 + seg * 8) ^ ((row & 7) << 3);
      *(u32x4*)&As[idx] = pk;
    }
#pragma unroll
    for (int i = 0; i < 4; ++i) {
      const int Cn = i * 256 + t;
      const int row = Cn >> 3, seg = Cn & 7;
      const float* bp = B + (size_t)(n0 + row) * ldb + kt + seg * 8;
      float4v f0 = *(const float4v*)bp;
      float4v f1 = *(const float4v*)(bp + 4);
      u32x4 pk = (u32x4){pk2(f0.x, f0.y), pk2(f0.z, f0.w), pk2(f1.x, f1.y), pk2(f1.z, f1.w)};
      const int idx = (row * 64 + seg * 8) ^ ((row & 7) << 3);
      *(u32x4*)&Bs[idx] = pk;
    }
    __syncthreads();

#pragma unroll
    for (int ks = 0; ks < 2; ++ks) {
      const int kk = ks * 32 + g * 8;
      short8 af[4], bf[4];
#pragma unroll
      for (int mi = 0; mi < 4; ++mi) {
        const int r = wm + mi * 16 + c;
        af[mi] = *(const short8*)&As[(r * 64 + kk) ^ ((r & 7) << 3)];
      }
#pragma unroll
      for (int ni = 0; ni < 4; ++ni) {
        const int r = wn + ni * 16 + c;
        bf[ni] = *(const short8*)&Bs[(r * 64 + kk) ^ ((r & 7) << 3)];
      }
#pragma unroll
      for (int mi = 0; mi < 4; ++mi)
#pragma unroll
        for (int ni = 0; ni < 4; ++ni) {
          if (CMODE == 2)
            acc[mi][ni] = __builtin_amdgcn_mfma_f32_16x16x32_bf16(bf[ni], af[mi], acc[mi][ni], 0, 0, 0);
          else
            acc[mi][ni] = __builtin_amdgcn_mfma_f32_16x16x32_bf16(af[mi], bf[ni], acc[mi][ni], 0, 0, 0);
        }
    }
  }

#pragma unroll
  for (int mi = 0; mi < 4; ++mi)
#pragma unroll
    for (int ni = 0; ni < 4; ++ni)
#pragma unroll
      for (int r = 0; r < 4; ++r) {
        if (CMODE == 2) {
          const int vr = vrow0 + wn + ni * 16 + g * 4 + r;
          const int sc = m0 + wm + mi * 16 + c;
          ((u16*)Cv)[(size_t)vr * ldc + sc] = f2bf(acc[mi][ni][r]);
        } else {
          const int row = m0 + wm + mi * 16 + g * 4 + r;
          const int col = n0 + wn + ni * 16 + c;
          if (CMODE == 1)
            ((u16*)Cv)[(size_t)row * ldc + col] = f2bf(acc[mi][ni][r]);
          else
            ((float*)Cv)[(size_t)row * ldc + col] = acc[mi][ni][r];
        }
      }
}

// ---------------------------------------------------------------------------
// RoPE (GPT-J interleaved) in-place on q and k sections of qkv (bf16).
// ---------------------------------------------------------------------------
__global__ __launch_bounds__(256)
void rope_kernel(u16* __restrict__ qkv, const int* __restrict__ pos32) {
  const int idx = blockIdx.x * 256 + threadIdx.x;
  const int s = idx >> 9;
  const int rem = idx & 511;
  const int h = rem >> 5, i = rem & 31;
  const bool is64 = (pos32[1] == 0);
  const int pv = is64 ? pos32[2 * s] : pos32[s];
  const float pos = (float)pv;
  const float inv_freq = expf(-(float)i * (9.210340371976184f / 32.0f));
  const float f = pos * inv_freq;
  const float cs = cosf(f), sn = sinf(f);
  u16* p = qkv + (size_t)s * QKVDIM + (h >> 1) * 1536 + (h & 1) * 256 + 2 * i;
  {
    float x1 = bf2f(p[0]), x2 = bf2f(p[1]);
    p[0] = f2bf(x1 * cs - x2 * sn);
    p[1] = f2bf(x2 * cs + x1 * sn);
  }
  {
    u16* pk_ = p + 1024;
    float x1 = bf2f(pk_[0]), x2 = bf2f(pk_[1]);
    pk_[0] = f2bf(x1 * cs - x2 * sn);
    pk_[1] = f2bf(x2 * cs + x1 * sn);
  }
}

// ---------------------------------------------------------------------------
// Flash attention, causal. Grid (16 pairs, 16 heads); block = 4 waves.
// Pass 0: q-tile bx; pass 1: q-tile 31-bx  -> uniform 68 KV-tiles per block.
// T14: next tile's K/V global loads issued into regs before compute, LDS
// writes after the post-compute barrier. T13 defer-rescale (THR=8). T5
// setprio around MFMA clusters.
// ---------------------------------------------------------------------------
__global__ __launch_bounds__(256)
void attn_kernel(const u16* __restrict__ qkv, const u16* __restrict__ vT,
                 u16* __restrict__ attnout) {
  __shared__ u16 Kl[32 * 256];
  __shared__ u16 Vl[256 * 40];
  __shared__ u16 Pl[4][16 * 40];

  const int t = threadIdx.x;
  const int w = t >> 6, lane = t & 63, g = lane >> 4, c = lane & 15;
  const int head = blockIdx.y;
  const int q_off = (head >> 1) * 1536 + (head & 1) * 256;
  const int k_off = q_off + 1024;
  const u16* vTh = vT + (size_t)(head * 256) * SEQ;

  // staging address components (constant per thread)
  const int kvK = t >> 5;                    // K-task kv row (i adds 8*i)
  const int segK = ((t & 31) ^ (kvK & 7));   // swizzle-compensated segment
  const int dV = t >> 2, q8V = (t & 3) * 8;  // V-task: d row (i adds 64*i)

  for (int pass = 0; pass < 2; ++pass) {
    const int qt = pass ? (31 - (int)blockIdx.x) : (int)blockIdx.x;
    const int qrow = qt * 64 + w * 16;
    const int nt = 2 * qt + 2;

    short8 qf[8];
    {
      const u16* qb = qkv + (size_t)(qrow + c) * QKVDIM + q_off + g * 8;
#pragma unroll
      for (int cc = 0; cc < 8; ++cc) qf[cc] = *(const short8*)(qb + cc * 32);
    }

    f32x4 o[16] = {};
    float mrow[4], lrow[4];
#pragma unroll
    for (int r = 0; r < 4; ++r) { mrow[r] = -3.0e38f; lrow[r] = 0.0f; }

    u32x4 kreg[4], vreg[4];
    // prologue: load tile 0 into regs
#pragma unroll
    for (int i = 0; i < 4; ++i)
      kreg[i] = *(const u32x4*)(qkv + (size_t)(kvK + i * 8) * QKVDIM + k_off + segK * 8);
#pragma unroll
    for (int i = 0; i < 4; ++i)
      vreg[i] = *(const u32x4*)(vTh + (size_t)(dV + i * 64) * SEQ + q8V);
    __syncthreads();  // previous pass/tile readers done before overwrite
#pragma unroll
    for (int i = 0; i < 4; ++i) *(u32x4*)&Kl[(i * 256 + t) * 8] = kreg[i];
#pragma unroll
    for (int i = 0; i < 4; ++i) *(u32x4*)&Vl[(dV + i * 64) * 40 + q8V] = vreg[i];

    for (int ti = 0; ti < nt; ++ti) {
      __syncthreads();  // staged tile ti visible
      const int kv0 = ti * 32;
      const bool more = (ti + 1 < nt);
      if (more) {  // T14: issue next tile's loads now; write after barrier
        const int kvn = kv0 + 32;
#pragma unroll
        for (int i = 0; i < 4; ++i)
          kreg[i] = *(const u32x4*)(qkv + (size_t)(kvn + kvK + i * 8) * QKVDIM + k_off + segK * 8);
#pragma unroll
        for (int i = 0; i < 4; ++i)
          vreg[i] = *(const u32x4*)(vTh + (size_t)(dV + i * 64) * SEQ + kvn + q8V);
      }

      if (kv0 <= qrow + 15) {
        f32x4 s0 = {}, s1 = {};
        __builtin_amdgcn_s_setprio(1);
#pragma unroll
        for (int cc = 0; cc < 8; ++cc) {
          const int d = cc * 32 + g * 8;
          short8 kf0 = *(const short8*)&Kl[(c * 256 + d) ^ ((c & 7) << 3)];
          s0 = __builtin_amdgcn_mfma_f32_16x16x32_bf16(qf[cc], kf0, s0, 0, 0, 0);
          short8 kf1 = *(const short8*)&Kl[((16 + c) * 256 + d) ^ ((c & 7) << 3)];
          s1 = __builtin_amdgcn_mfma_f32_16x16x32_bf16(qf[cc], kf1, s1, 0, 0, 0);
        }
        __builtin_amdgcn_s_setprio(0);

        const bool domask = (kv0 + 31 > qrow);
        float sv0[4], sv1[4];
#pragma unroll
        for (int r = 0; r < 4; ++r) {
          sv0[r] = s0[r] * SCALE;
          sv1[r] = s1[r] * SCALE;
          if (domask) {
            const int qg = qrow + g * 4 + r;
            if (kv0 + c > qg) sv0[r] = -3.0e38f;
            if (kv0 + 16 + c > qg) sv1[r] = -3.0e38f;
          }
        }
        // row maxima (16-lane groups)
        float tm[4];
#pragma unroll
        for (int r = 0; r < 4; ++r) {
          float v = fmaxf(sv0[r], sv1[r]);
#pragma unroll
          for (int off = 1; off < 16; off <<= 1) v = fmaxf(v, __shfl_xor(v, off));
          tm[r] = v;
        }
        // T13: defer rescale unless some row grew past THR=8
        float need = tm[0] - mrow[0];
#pragma unroll
        for (int r = 1; r < 4; ++r) need = fmaxf(need, tm[r] - mrow[r]);
        const bool doresc = !__all(need <= 8.0f);
        float corr[4] = {1.0f, 1.0f, 1.0f, 1.0f};
        if (doresc) {
#pragma unroll
          for (int r = 0; r < 4; ++r) {
            const float mnew = fmaxf(mrow[r], tm[r]);
            corr[r] = __expf(mrow[r] - mnew);
            mrow[r] = mnew;
          }
#pragma unroll
          for (int dt = 0; dt < 16; ++dt)
#pragma unroll
            for (int r = 0; r < 4; ++r) o[dt][r] *= corr[r];
        }
#pragma unroll
        for (int r = 0; r < 4; ++r) {
          const float p0 = __expf(sv0[r] - mrow[r]);
          const float p1 = __expf(sv1[r] - mrow[r]);
          Pl[w][(g * 4 + r) * 40 + c] = f2bf(p0);
          Pl[w][(g * 4 + r) * 40 + 16 + c] = f2bf(p1);
          float rs = p0 + p1;
#pragma unroll
          for (int off = 1; off < 16; off <<= 1) rs += __shfl_xor(rs, off);
          lrow[r] = lrow[r] * corr[r] + rs;
        }

        asm volatile("s_waitcnt lgkmcnt(0)" ::: "memory");  // P visible (own wave)
        __builtin_amdgcn_sched_barrier(0);

        const short8 pa = *(const short8*)&Pl[w][c * 40 + g * 8];
        __builtin_amdgcn_s_setprio(1);
#pragma unroll
        for (int dt = 0; dt < 16; ++dt) {
          const short8 bv = *(const short8*)&Vl[(dt * 16 + c) * 40 + g * 8];
          o[dt] = __builtin_amdgcn_mfma_f32_16x16x32_bf16(pa, bv, o[dt], 0, 0, 0);
        }
        __builtin_amdgcn_s_setprio(0);
      }

      __syncthreads();  // all reads of tile ti done
      if (more) {
#pragma unroll
        for (int i = 0; i < 4; ++i) *(u32x4*)&Kl[(i * 256 + t) * 8] = kreg[i];
#pragma unroll
        for (int i = 0; i < 4; ++i) *(u32x4*)&Vl[(dV + i * 64) * 40 + q8V] = vreg[i];
      }
    }

    // epilogue: normalize and write attn[s][head*256 + d] (bf16)
    float inv[4];
#pragma unroll
    for (int r = 0; r < 4; ++r) inv[r] = 1.0f / lrow[r];
#pragma unroll
    for (int dt = 0; dt < 16; ++dt)
#pragma unroll
      for (int r = 0; r < 4; ++r) {
        const int row = qrow + g * 4 + r;
        attnout[(size_t)row * HID + head * 256 + dt * 16 + c] = f2bf(o[dt][r] * inv[r]);
      }
  }
}

// ---------------------------------------------------------------------------
extern "C" void kernel_launch(void* const* d_in, const int* in_sizes, int n_in,
                              void* d_out, int out_size, void* d_ws, size_t ws_size,
                              hipStream_t stream) {
  const float* hidden = (const float*)d_in[0];
  const int* positions = (const int*)d_in[1];
  const float* w_qkv = (const float*)d_in[2];
  const float* w_out = (const float*)d_in[3];
  float* out = (float*)d_out;

  u16* qkv = (u16*)d_ws;                            // 48 MiB
  u16* attn = qkv + (size_t)SEQ * QKVDIM;           // 16 MiB
  u16* vT = attn + (size_t)SEQ * HID;               // 16 MiB
  u16* hid_bf = vT + (size_t)HID * SEQ;             // 16 MiB
  u16* wqkv_bf = hid_bf + (size_t)SEQ * HID;        // 96 MiB
  u16* wout_bf = wqkv_bf + (size_t)QKVDIM * HID;    // 32 MiB

  const size_t need = ((size_t)SEQ * QKVDIM + (size_t)SEQ * HID * 2 +
                       (size_t)HID * SEQ + (size_t)QKVDIM * HID +
                       (size_t)HID * HID) * 2;      // 224 MiB

  if (ws_size >= need) {
    conv_kernel<<<2048, 256, 0, stream>>>(hidden, hid_bf, SEQ * HID / 8);
    conv_kernel<<<2048, 256, 0, stream>>>(w_qkv, wqkv_bf, QKVDIM * HID / 8);
    conv_kernel<<<2048, 256, 0, stream>>>(w_out, wout_bf, HID * HID / 8);
    gemm_fast<1><<<dim3(64, SEQ / 128), 256, 0, stream>>>(
        hid_bf, wqkv_bf, qkv, HID, HID, HID, QKVDIM);
    gemm_fast<2><<<dim3(32, SEQ / 128), 256, 0, stream>>>(
        hid_bf, wqkv_bf, vT, HID, HID, HID, SEQ);
    rope_kernel<<<(SEQ * 512) / 256, 256, 0, stream>>>(qkv, positions);
    attn_kernel<<<dim3(16, 16), 256, 0, stream>>>(qkv, vT, attn);
    gemm_fast<0><<<dim3(HID / 128, SEQ / 128), 256, 0, stream>>>(
        attn, wout_bf, out, HID, HID, HID, HID);
  } else {
    gemm_bt<0, 1><<<dim3(64, SEQ / 128), 256, 0, stream>>>(
        hidden, w_qkv, qkv, HID, HID, HID, QKVDIM);
    gemm_bt<0, 2><<<dim3(32, SEQ / 128), 256, 0, stream>>>(
        hidden, w_qkv, vT, HID, HID, HID, SEQ);
    rope_kernel<<<(SEQ * 512) / 256, 256, 0, stream>>>(qkv, positions);
    attn_kernel<<<dim3(16, 16), 256, 0, stream>>>(qkv, vT, attn);
    gemm_bt<1, 0><<<dim3(HID / 128, SEQ / 128), 256, 0, stream>>>(
        attn, w_out, out, HID, HID, HID, HID);
  }
}